// Round 14
// baseline (239.307 us; speedup 1.0000x reference)
//
#include <hip/hip_runtime.h>
#include <hip/hip_fp16.h>
#include <math.h>

#define NSEG 126
#define PI_F 3.14159265358979323846f

__device__ __forceinline__ unsigned bitrev8(unsigned v) { return __brev(v) >> 24; }
__device__ __forceinline__ unsigned bitrev6(unsigned v) { return __brev(v) >> 26; }
__device__ __forceinline__ float2 cmulc(float2 a, float2 b) {
    return make_float2(a.x*b.x - a.y*b.y, a.x*b.y + a.y*b.x);
}
__device__ __forceinline__ float2 mulmi(float2 a){ return make_float2(a.y, -a.x); }
__device__ __forceinline__ float2 h2f2(unsigned u) {           // scalar, no memory
    __half2 h = __builtin_bit_cast(__half2, u);
    return __half22float2(h);
}
__device__ __forceinline__ unsigned f2h2(float2 v) {
    return __builtin_bit_cast(unsigned, __float22half2_rn(v));
}

// ---------------------------------------------------------------------------
// v2 core, SIZED-REFERENCE params (SROA-safe): layout p = 4*lane + i,
// exit x[k][i] = X[bitrev8(p)]. 4 sincos total, shared across K.
// ---------------------------------------------------------------------------
template <int K>
__device__ __forceinline__ void stage_shfl(float2 (&x)[K][4], int lane, int hl,
                                           float2 w0, float2 st1, float2 st2, float2 st3)
{
    float2 w1 = cmulc(w0, st1), w2 = cmulc(w0, st2), w3 = cmulc(w0, st3);
    bool up = (lane & hl) != 0;
    #pragma unroll
    for (int k = 0; k < K; k++) {
        #pragma unroll
        for (int i = 0; i < 4; i++) {
            float2 wi = (i == 0) ? w0 : (i == 1) ? w1 : (i == 2) ? w2 : w3;
            float px = __shfl_xor(x[k][i].x, hl);
            float py = __shfl_xor(x[k][i].y, hl);
            if (up) {
                float dx = px - x[k][i].x, dy = py - x[k][i].y;
                x[k][i] = make_float2(dx*wi.x - dy*wi.y, dx*wi.y + dy*wi.x);
            } else {
                x[k][i] = make_float2(x[k][i].x + px, x[k][i].y + py);
            }
        }
    }
}

template <int K>
__device__ __forceinline__ void fft256_v2(float2 (&x)[K][4], int lane) {
    { float s,c; __sincosf(-PI_F*(float)(lane&31)*(1.0f/32.0f), &s,&c);   // h=128
      stage_shfl<K>(x,lane,32, make_float2(c,s),
        make_float2(0.99969882f,-0.02454123f),
        make_float2(0.99879546f,-0.04906767f),
        make_float2(0.99729046f,-0.07356456f)); }
    { float s,c; __sincosf(-PI_F*(float)(lane&15)*(1.0f/16.0f), &s,&c);   // h=64
      stage_shfl<K>(x,lane,16, make_float2(c,s),
        make_float2(0.99879546f,-0.04906767f),
        make_float2(0.99518473f,-0.09801714f),
        make_float2(0.98917651f,-0.14673047f)); }
    { float s,c; __sincosf(-PI_F*(float)(lane&7)*(1.0f/8.0f), &s,&c);     // h=32
      stage_shfl<K>(x,lane,8, make_float2(c,s),
        make_float2(0.99518473f,-0.09801714f),
        make_float2(0.98078528f,-0.19509032f),
        make_float2(0.95694034f,-0.29028468f)); }
    { float s,c; __sincosf(-PI_F*(float)(lane&3)*(1.0f/4.0f), &s,&c);     // h=16
      stage_shfl<K>(x,lane,4, make_float2(c,s),
        make_float2(0.98078528f,-0.19509032f),
        make_float2(0.92387953f,-0.38268343f),
        make_float2(0.83146961f,-0.55557023f)); }
    { float2 w0 = (lane&1) ? make_float2(0.f,-1.f) : make_float2(1.f,0.f); // h=8
      stage_shfl<K>(x,lane,2, w0,
        make_float2(0.92387953f,-0.38268343f),
        make_float2(0.70710678f,-0.70710678f),
        make_float2(0.38268343f,-0.92387953f)); }
    { stage_shfl<K>(x,lane,1, make_float2(1.f,0.f),                        // h=4
        make_float2(0.70710678f,-0.70710678f),
        make_float2(0.f,-1.f),
        make_float2(-0.70710678f,-0.70710678f)); }
    #pragma unroll
    for (int k = 0; k < K; k++) {                                          // h=2, h=1
        float2 u, v;
        u=x[k][0]; v=x[k][2]; x[k][0]=make_float2(u.x+v.x,u.y+v.y); x[k][2]=make_float2(u.x-v.x,u.y-v.y);
        u=x[k][1]; v=x[k][3]; x[k][1]=make_float2(u.x+v.x,u.y+v.y); x[k][3]=mulmi(make_float2(u.x-v.x,u.y-v.y));
        u=x[k][0]; v=x[k][1]; x[k][0]=make_float2(u.x+v.x,u.y+v.y); x[k][1]=make_float2(u.x-v.x,u.y-v.y);
        u=x[k][2]; v=x[k][3]; x[k][2]=make_float2(u.x+v.x,u.y+v.y); x[k][3]=make_float2(u.x-v.x,u.y-v.y);
    }
}

// ---------------------------------------------------------------------------
// Fused prep (R11 format): bucket j = 255-c; pack r | mirror(r)<<8 | seg<<16.
// ---------------------------------------------------------------------------
__global__ __launch_bounds__(1024) void prep_all(
    const int* __restrict__ rr, const int* __restrict__ cc,
    const int* __restrict__ seg, int n,
    int* __restrict__ starts, int* __restrict__ b_pack, float* __restrict__ acc)
{
    __shared__ int cnt[128];
    __shared__ int cur[128];
    int tid = threadIdx.x;
    if (tid < NSEG * 3) acc[tid] = 0.f;
    if (tid < 128) cnt[tid] = 0;
    __syncthreads();
    for (int i = tid; i < n; i += 1024) {
        int c = cc[i], r = rr[i];
        if ((c > 128) || (c == 128 && r > 128)) atomicAdd(&cnt[255 - c], 1);
    }
    __syncthreads();
    if (tid < 64) {
        int2 c2 = reinterpret_cast<const int2*>(cnt)[tid];
        int lsum = c2.x + c2.y;
        int pre = lsum;
        #pragma unroll
        for (int off = 1; off < 64; off <<= 1) {
            int v = __shfl_up(pre, off);
            if (tid >= off) pre += v;
        }
        int excl = pre - lsum;
        int2 outv = make_int2(excl, excl + c2.x);
        reinterpret_cast<int2*>(cur)[tid] = outv;
        reinterpret_cast<int2*>(starts)[tid] = outv;
        if (tid == 63) starts[128] = excl + c2.x + c2.y;
    }
    __syncthreads();
    for (int i = tid; i < n; i += 1024) {
        int c = cc[i], r = rr[i];
        if ((c > 128) || (c == 128 && r > 128)) {
            int j = 255 - c;
            int pos = atomicAdd(&cur[j], 1);
            b_pack[pos] = r | (((256 - r) & 255) << 8) | (seg[i] << 16);
        }
    }
}

// ---------------------------------------------------------------------------
// Row-pass: v2 FFT, float4 loads, fp16 Gt; row q holds X[bitrev8(q)].
// ---------------------------------------------------------------------------
__global__ __launch_bounds__(512, 1) void rowfft_kernel(
    const float* __restrict__ inp, const float* __restrict__ tgt,
    unsigned* __restrict__ G, int pair_base)
{
    __shared__ unsigned T[256 * 17];             // 17408 B (half2 as uint)
    int tid    = threadIdx.x;
    int wv     = tid >> 6;
    int lane   = tid & 63;
    int plocal = blockIdx.x >> 3;
    int rowgrp = blockIdx.x & 7;                  // 32 rows each
    int row0   = (rowgrp << 5) + (wv << 2);
    size_t base = (((size_t)(pair_base + plocal)) << 16) + ((size_t)row0 << 8);
    const float4* s1 = (const float4*)(inp + base);
    const float4* s2 = (const float4*)(tgt + base);

    float2 x[4][4];
    #pragma unroll
    for (int k = 0; k < 4; k++) {
        float4 A = s1[k * 64 + lane];
        float4 B = s2[k * 64 + lane];
        x[k][0] = make_float2(A.x, B.x);
        x[k][1] = make_float2(A.y, B.y);
        x[k][2] = make_float2(A.z, B.z);
        x[k][3] = make_float2(A.w, B.w);
    }
    fft256_v2<4>(x, lane);

    unsigned* dst = G + (((size_t)plocal) << 16) + (rowgrp << 5);
    #pragma unroll
    for (int pass = 0; pass < 2; pass++) {
        if ((wv >> 2) == pass) {                  // waves 0-3 then 4-7
            int xr = ((wv & 3) << 2);
            #pragma unroll
            for (int k = 0; k < 4; k++)
                #pragma unroll
                for (int i = 0; i < 4; i++)
                    T[(4 * lane + i) * 17 + xr + k] = f2h2(x[k][i]);
        }
        __syncthreads();
        int xl = tid & 15;
        int qq = tid >> 4;                        // 0..31
        #pragma unroll
        for (int ii = 0; ii < 8; ii++) {
            int q = qq + (ii << 5);
            dst[q * 256 + (pass << 4) + xl] = T[q * 17 + xl];
        }
        __syncthreads();
    }
}

// ---------------------------------------------------------------------------
// Column-pass + gather (R13 structure, scratch-free conversions, single accl).
// ---------------------------------------------------------------------------
__global__ __launch_bounds__(512, 1) void colfft_gather_kernel(
    const unsigned* __restrict__ G, const int* __restrict__ starts,
    const int* __restrict__ b_pack, float* __restrict__ acc)
{
    __shared__ float2 Fb[8 * 512];               // 32 KiB
    __shared__ float accl[NSEG * 3];
    int tid    = threadIdx.x;
    int wv     = tid >> 6;
    int lane   = tid & 63;
    int plocal = blockIdx.x >> 2;
    int b      = blockIdx.x & 3;
    int jb0    = (b << 5) + (wv << 2);           // wave buckets [jb0, jb0+4)

    for (int i = tid; i < NSEG * 3; i += 512) accl[i] = 0.f;
    __syncthreads();

    const unsigned* Gp = G + (((size_t)plocal) << 16);
    float2 x[8][4];
    #pragma unroll
    for (int t = 0; t < 4; t++) {
        int j = jb0 + t;
        int q_lo = (int)bitrev8((unsigned)(j + 1));
        int q_hi = (int)bitrev8((unsigned)(255 - j));
        uint4 rl = ((const uint4*)(Gp + ((size_t)q_lo << 8)))[lane];
        uint4 rh = ((const uint4*)(Gp + ((size_t)q_hi << 8)))[lane];
        x[2*t][0]   = h2f2(rl.x); x[2*t][1]   = h2f2(rl.y);
        x[2*t][2]   = h2f2(rl.z); x[2*t][3]   = h2f2(rl.w);
        x[2*t+1][0] = h2f2(rh.x); x[2*t+1][1] = h2f2(rh.y);
        x[2*t+1][2] = h2f2(rh.z); x[2*t+1][3] = h2f2(rh.w);
    }

    fft256_v2<8>(x, lane);

    float2* slot = Fb + (wv << 9);               // 4 KiB per wave, reused 4x
    int nb = (int)bitrev6((unsigned)lane);
    const int BR2[4] = {0, 2, 1, 3};
    #pragma unroll
    for (int t = 0; t < 4; t++) {
        #pragma unroll
        for (int i = 0; i < 4; i++) {
            slot[nb + (BR2[i] << 6)]       = x[2*t][i];     // F_lo natural
            slot[256 + nb + (BR2[i] << 6)] = x[2*t+1][i];   // F_hi natural
        }
        int j = jb0 + t;
        int s0 = starts[j], s1 = starts[j + 1];
        int e  = s0 + lane;
        int pk = (e < s1) ? b_pack[e] : 0;
        while (e < s1) {
            int e2  = e + 64;
            int pk2 = (e2 < s1) ? b_pack[e2] : 0;
            float2 a = slot[256 + (pk & 255)];        // Fp(r, c)
            float2 m = slot[(pk >> 8) & 255];         // Fp(-r, -c)
            int sg = pk >> 16;
            float f1x = a.x + m.x, f1y = a.y - m.y;   // 2*F1
            float dx  = a.x - m.x, dy  = a.y + m.y;   // 2i*F2
            atomicAdd(&accl[sg * 3 + 0], f1x * dy - f1y * dx);
            atomicAdd(&accl[sg * 3 + 1], f1x * f1x + f1y * f1y);
            atomicAdd(&accl[sg * 3 + 2], dx * dx + dy * dy);
            e = e2; pk = pk2;
        }
    }
    __syncthreads();

    for (int i = tid; i < NSEG * 3; i += 512) {
        float v = accl[i];
        if (v != 0.f) atomicAdd(&acc[i], v);
    }
}

// ---------------------------------------------------------------------------
__global__ void final_kernel(const float* __restrict__ acc, const float* __restrict__ w,
                             float* __restrict__ out, float scale) {
    int lane = threadIdx.x;
    float val = 0.f;
    for (int s = lane; s < NSEG; s += 64) {
        float cr = acc[s * 3 + 0];
        float p1 = acc[s * 3 + 1];
        float p2 = acc[s * 3 + 2];
        float den = p1 * p2;
        float curve = den > 0.f ? fabsf(cr) * rsqrtf(den) : 0.f;
        val += curve * w[s + 1];
    }
    if (lane == 0) val += w[0];
    #pragma unroll
    for (int off = 32; off > 0; off >>= 1) val += __shfl_down(val, off);
    if (lane == 0) out[0] = scale * val;
}

// ---------------------------------------------------------------------------
extern "C" void kernel_launch(void* const* d_in, const int* in_sizes, int n_in,
                              void* d_out, int out_size, void* d_ws, size_t ws_size,
                              hipStream_t stream)
{
    const float* inp = (const float*)d_in[0];
    const float* tgt = (const float*)d_in[1];
    const float* wts = (const float*)d_in[2];
    const int*   rr  = (const int*)d_in[3];
    const int*   cc  = (const int*)d_in[4];
    const int*   sg  = (const int*)d_in[5];
    int npts   = in_sizes[3];
    int npairs = in_sizes[0] >> 16;               // B*C (65536 px/img)

    char* ws = (char*)d_ws;
    float* acc    = (float*)(ws + 0);             // 378 floats
    int*   starts = (int*)(ws + 2048);            // 129 ints
    int*   b_pack = (int*)(ws + 4096);
    size_t goff = 4096 + (size_t)npts * 4;
    goff = (goff + 255) & ~(size_t)255;
    unsigned* G = (unsigned*)(ws + goff);

    size_t per_pair = (size_t)256 * 256 * 4;      // 256 KiB (half2 as uint)
    int maxchunk = (int)((ws_size > goff ? (ws_size - goff) : 0) / per_pair);
    if (maxchunk < 1) maxchunk = 1;
    if (maxchunk > npairs) maxchunk = npairs;

    prep_all<<<1, 1024, 0, stream>>>(rr, cc, sg, npts, starts, b_pack, acc);

    for (int pb = 0; pb < npairs; pb += maxchunk) {
        int cp = npairs - pb < maxchunk ? npairs - pb : maxchunk;
        rowfft_kernel<<<cp * 8, 512, 0, stream>>>(inp, tgt, G, pb);
        colfft_gather_kernel<<<cp * 4, 512, 0, stream>>>(G, starts, b_pack, acc);
    }

    final_kernel<<<1, 64, 0, stream>>>(acc, wts, (float*)d_out, (float)npairs);
}